// Round 1
// 436.368 us; speedup vs baseline: 1.0549x; 1.0549x over previous
//
#include <hip/hip_runtime.h>
#include <math.h>

#define Bb 8
#define Nn 2048
#define Mm 2048
#define Cc 512

typedef __attribute__((ext_vector_type(8))) _Float16 hfrag;  // 8 f16 = 4 VGPRs
typedef __attribute__((ext_vector_type(4))) float f4;        // MFMA acc
typedef __attribute__((ext_vector_type(4))) _Float16 h4;

__device__ __forceinline__ void gld16(const void* g, void* l) {
    __builtin_amdgcn_global_load_lds(
        (const __attribute__((address_space(1))) void*)g,
        (__attribute__((address_space(3))) void*)l, 16, 0, 0);
}

// ---------------------------------------------------------------------------
// MFMA GEMM (f16 in, fp32 acc), 128xBN tile, BK=64 (two stacked 32-wide
// panels -> same benign LDS bank pattern, linear global_load_lds dests,
// HALF the barrier/vmcnt-drain count), 256 threads.
// C[r][c] = sum_k A[r][k]*Bt[c][k];  A,Bt k-contiguous.
// ALL epilogues store C TRANSPOSED: per (i,j) frag the 4 regs are 4
// consecutive rows -> contiguous 8B/16B stores at [col][row].
//   BN=128: 4 waves 2x2, each 64x64 (acc 4x4).
//   BN=64 : 4 waves row-stacked, each 32x64 (acc 2x4).
// SWZ: 0 plain 2-D (bz=0); 1: bz=id&7 (batch->XCD), bx=(id>>3)%GX, by=/GX.
//      2: bz=0, bx=(id>>3)%GX, by=(id&7)+8*((id>>3)/GX).
// EPI 0: score^T + softmax phase1. A=enc(rows=m), B=dec(cols=n).
//        acc=score[n][m]; *mask[n][m] (f4 along m, software-pipelined over
//        j-columns); per-(n,t) m0,l0 (2 shfl); e[n][m]=exp(s-m0) f16 h4
//        stores (masked->0); mlq[(bz,n,t)]=(m0,l0).
// EPI 1: vT. A=enc(rows=bm), Bt=Wv^T(cols=c). vT[b][c][m] = acc+bv[c], h4.
// EPI 2: PV+gate. A=vT(rows=c), B=e(cols=n), B-frags *= alpha(n,t).
//        g[n][c] = dec_h[n][c]*(1+tanh(acc)), h4 loads+stores.
// EPI 3: fc1. A=W1^T(rows=c2), B=g(cols=n). h[n][c2]=relu(acc+b1[c2]), h4.
// EPI 4: fc2. A=W2^T(rows=c3), B=h(cols=n). out[n][c3]=acc+b2[c3], f4 stores.
// ---------------------------------------------------------------------------
template<int EPI, int BN, int SWZ>
__global__ __launch_bounds__(256) void gemm_mfma(
    const _Float16* __restrict__ Ah, long sA, int lda,
    const _Float16* __restrict__ Bh, long sB, int ldb,
    const float* __restrict__ aux, long sAux, int ldaux,     // mask / f32 bias
    const _Float16* __restrict__ aux2,                       // EPI2: dec_h
    float* __restrict__ mlal,          // EPI0: (m,l) out; EPI2: alpha in
    void* __restrict__ Cout, long sC, int ldc, int K, int GX)
{
    constexpr int NI = (BN == 128) ? 4 : 2;
    // BK=64 staging: A = 1024 slots of 16B (2 panels x 128 rows x 4 groups),
    // B = BN*8 slots. One issue = 256 threads x 16B = 256 slots.
    constexpr int NQ = (1024 + BN * 8) / 256;

    __shared__ _Float16 As[2 * 128 * 32];
    __shared__ _Float16 Bs[2 * BN * 32];

    int bx, by, bz;
    if (SWZ == 1) {
        const int id = blockIdx.x;
        bz = id & 7; bx = (id >> 3) % GX; by = (id >> 3) / GX;
    } else if (SWZ == 2) {
        const int id = blockIdx.x;
        bz = 0; bx = (id >> 3) % GX; by = (id & 7) + 8 * ((id >> 3) / GX);
    } else {
        bx = blockIdx.x; by = blockIdx.y; bz = 0;
    }

    const _Float16* A0 = Ah + (size_t)bz * sA;
    const _Float16* B0 = Bh + (size_t)bz * sB;

    const int tid  = threadIdx.x;
    const int wv   = tid >> 6;
    const int ln   = tid & 63;
    const int wx   = (BN == 128) ? (wv & 1) : 0;
    const int wy   = (BN == 128) ? (wv >> 1) : wv;
    const int lcol = ln & 15, quad = ln >> 4;
    const int row0w = wy * (NI * 16);
    const int col0w = wx * 64;

    const int rowBase = by * 128;
    const int colBase = bx * BN;

    f4 acc[NI][4];
    const f4 z4 = {0.f, 0.f, 0.f, 0.f};
    #pragma unroll
    for (int i = 0; i < NI; ++i)
        #pragma unroll
        for (int j = 0; j < 4; ++j) acc[i][j] = z4;

    // EPI2: per-batch alpha base, refreshed per 64-k tile (= per k-step now)
    const float* alb = (EPI == 2) ? (mlal + (size_t)bz * (2048 * 32)) : nullptr;
    _Float16 als[4] = {(_Float16)0.f, (_Float16)0.f, (_Float16)0.f, (_Float16)0.f};

    for (int k0 = 0; k0 < K; k0 += 64) {
        __syncthreads();
        #pragma unroll
        for (int q = 0; q < NQ; ++q) {
            const int c0 = q * 256 + wv * 64;
            const int c  = c0 + ln;
            if (c0 < 1024) {
                // A slot c = panel*512 + row*4 + group
                const int hh = c >> 9;
                const int r  = (c >> 2) & 127;
                const int ko = hh * 32 + (c & 3) * 8;
                gld16(A0 + (size_t)(rowBase + r) * lda + k0 + ko, &As[c0 * 8]);
            } else {
                const int cb = c - 1024;
                const int hh = cb / (BN * 4);
                const int r  = (cb >> 2) & (BN - 1);
                const int ko = hh * 32 + (cb & 3) * 8;
                gld16(B0 + (size_t)(colBase + r) * ldb + k0 + ko, &Bs[(c0 - 1024) * 8]);
            }
        }
        __syncthreads();

        if (EPI == 2) {        // alpha(n, t): one 64-wide m-tile per k-step
            const int t = k0 >> 6;
            #pragma unroll
            for (int j = 0; j < 4; ++j) {
                const int n = colBase + col0w + j * 16 + lcol;
                als[j] = (_Float16)alb[(size_t)n * 32 + t];
            }
        }

        #pragma unroll
        for (int hh = 0; hh < 2; ++hh) {
            hfrag af[NI], bf_[4];
            const int aoff = quad * 8;
            #pragma unroll
            for (int i = 0; i < NI; ++i)
                af[i]  = *(const hfrag*)&As[hh * 4096 + (row0w + i * 16 + lcol) * 32 + aoff];
            #pragma unroll
            for (int j = 0; j < 4; ++j)
                bf_[j] = *(const hfrag*)&Bs[hh * (BN * 32) + (col0w + j * 16 + lcol) * 32 + aoff];

            if (EPI == 2) {
                #pragma unroll
                for (int j = 0; j < 4; ++j) bf_[j] = bf_[j] * als[j];
            }

            #pragma unroll
            for (int i = 0; i < NI; ++i)
                #pragma unroll
                for (int j = 0; j < 4; ++j)
                    acc[i][j] = __builtin_amdgcn_mfma_f32_16x16x32_f16(af[i], bf_[j], acc[i][j], 0, 0, 0);
        }
    }

    // C/D layout: col = lane&15, row = quad*4 + reg   [verified m89/m91]
    const int crow0 = rowBase + row0w + quad * 4;
    const int ccol0 = colBase + col0w + lcol;

    if (EPI == 0) {  // score^T + softmax phase 1 (BN=128): rows=m, cols=n
        _Float16* E = (_Float16*)Cout + (size_t)bz * sC;   // e[n][m], ld=ldc
        const float* Mk = aux + (size_t)bz * sAux;          // mask[n][m]
        const int t = (rowBase + row0w) >> 6;      // 64-wide m-tile index

        // mask loads grouped per column, software-pipelined across j:
        // column j+1's 4 loads are issued before column j's softmax VALU.
        f4 mk[NI];
        #pragma unroll
        for (int i = 0; i < NI; ++i)
            mk[i] = *(const f4*)(Mk + (size_t)ccol0 * ldaux + crow0 + i * 16);

        #pragma unroll
        for (int j = 0; j < 4; ++j) {
            const int n = ccol0 + j * 16;
            f4 mkn[NI];
            if (j < 3) {
                #pragma unroll
                for (int i = 0; i < NI; ++i)
                    mkn[i] = *(const f4*)(Mk + (size_t)(n + 16) * ldaux + crow0 + i * 16);
            }
            #pragma unroll
            for (int i = 0; i < NI; ++i)
                #pragma unroll
                for (int r = 0; r < 4; ++r) acc[i][j][r] *= mk[i][r];

            float mx = acc[0][j][0];
            #pragma unroll
            for (int i = 0; i < NI; ++i)
                #pragma unroll
                for (int r = 0; r < 4; ++r) mx = fmaxf(mx, acc[i][j][r]);
            mx = fmaxf(mx, __shfl_xor(mx, 16, 64));
            mx = fmaxf(mx, __shfl_xor(mx, 32, 64));
            float l0 = 0.f;
            #pragma unroll
            for (int i = 0; i < NI; ++i) {
                h4 ev;
                #pragma unroll
                for (int r = 0; r < 4; ++r) {
                    const float s = acc[i][j][r];
                    const float e = __expf(s - mx);
                    l0 += e;
                    ev[r] = (s == 0.f) ? (_Float16)0.f : (_Float16)e;
                }
                *(h4*)(E + (size_t)n * ldc + crow0 + i * 16) = ev;
            }
            l0 += __shfl_xor(l0, 16, 64);
            l0 += __shfl_xor(l0, 32, 64);
            if (quad == 0) {
                float2 p; p.x = mx; p.y = l0;
                ((float2*)mlal)[((size_t)bz * 2048 + n) * 32 + t] = p;
            }
            if (j < 3) {
                #pragma unroll
                for (int i = 0; i < NI; ++i) mk[i] = mkn[i];
            }
        }
    } else if (EPI == 1) {     // v^T: vT[b][c][m] = acc + bias[c], h4
        _Float16* C = (_Float16*)Cout;
        #pragma unroll
        for (int j = 0; j < 4; ++j) {
            const int col = ccol0 + j * 16;          // c index
            const float bi = aux[col];
            #pragma unroll
            for (int i = 0; i < NI; ++i) {
                const int rowb = crow0 + i * 16;     // flattened b*M + m
                const int bb = rowb >> 11, ml = rowb & 2047;
                h4 st;
                #pragma unroll
                for (int r = 0; r < 4; ++r) st[r] = (_Float16)(acc[i][j][r] + bi);
                *(h4*)(C + (size_t)bb * ((size_t)Cc * Mm) + (size_t)col * Mm + ml) = st;
            }
        }
    } else if (EPI == 2) {     // gate: g[n][c] = dec_h[n][c]*(1+tanh(acc))
        _Float16* C = (_Float16*)Cout + (size_t)bz * sC;
        const _Float16* Dg = aux2 + (size_t)bz * sC;
        #pragma unroll
        for (int i = 0; i < NI; ++i) {
            const int c0 = crow0 + i * 16;
            #pragma unroll
            for (int j = 0; j < 4; ++j) {
                const int n = ccol0 + j * 16;
                const h4 dv = *(const h4*)(Dg + (size_t)n * ldc + c0);
                h4 gv;
                #pragma unroll
                for (int r = 0; r < 4; ++r) {
                    const float a = acc[i][j][r];
                    const float th = 1.f - 2.f / (__expf(2.f * a) + 1.f);
                    gv[r] = (_Float16)((float)dv[r] * (1.f + th));
                }
                *(h4*)(C + (size_t)n * ldc + c0) = gv;
            }
        }
    } else if (EPI == 3) {     // fc1: h[n][c2] = relu(acc + b1[c2]), h4
        _Float16* C = (_Float16*)Cout;
        #pragma unroll
        for (int i = 0; i < NI; ++i) {
            const int c0 = crow0 + i * 16;
            const f4 bi = *(const f4*)(aux + c0);
            #pragma unroll
            for (int j = 0; j < 4; ++j) {
                const int n = ccol0 + j * 16;
                h4 hv;
                #pragma unroll
                for (int r = 0; r < 4; ++r)
                    hv[r] = (_Float16)fmaxf(acc[i][j][r] + bi[r], 0.f);
                *(h4*)(C + (size_t)n * ldc + c0) = hv;
            }
        }
    } else {                   // fc2: out[n][c3] = acc + b2[c3], f4 stores
        float* C = (float*)Cout;
        #pragma unroll
        for (int i = 0; i < NI; ++i) {
            const int c0 = crow0 + i * 16;
            const f4 bi = *(const f4*)(aux + c0);
            #pragma unroll
            for (int j = 0; j < 4; ++j) {
                const int n = ccol0 + j * 16;
                f4 ov;
                #pragma unroll
                for (int r = 0; r < 4; ++r) ov[r] = acc[i][j][r] + bi[r];
                *(f4*)(C + (size_t)n * ldc + c0) = ov;
            }
        }
    }
}

// ---------------------------------------------------------------------------
// Combine softmax partials: per row, m = max_t m_t, l = sum_t l_t*exp(m_t-m),
// alpha(row,t) = exp(m_t-m)/l.  One thread per row, 64-thread blocks.
// ---------------------------------------------------------------------------
__global__ __launch_bounds__(64) void combine_kernel(
    const float* __restrict__ mlq, float* __restrict__ alpha)
{
    const int row = blockIdx.x * 64 + threadIdx.x;   // 0..16383
    const float2* ml = (const float2*)mlq + (size_t)row * 32;
    float mt[32], lt[32];
    float m = -1e30f;
    #pragma unroll
    for (int t = 0; t < 32; ++t) {
        float2 p = ml[t];
        mt[t] = p.x; lt[t] = p.y;
        m = fmaxf(m, p.x);
    }
    float et[32], l = 0.f;
    #pragma unroll
    for (int t = 0; t < 32; ++t) {
        et[t] = __expf(mt[t] - m);
        l += lt[t] * et[t];
    }
    const float inv = 1.f / l;
    float* ap = alpha + (size_t)row * 32;
    #pragma unroll
    for (int t = 0; t < 32; ++t) ap[t] = et[t] * inv;
}

// fp32 -> f16, vectorized x4. grid*256*4 == element count.
__global__ __launch_bounds__(256) void sconv(const float* __restrict__ x,
                                             _Float16* __restrict__ o)
{
    const size_t i = (size_t)blockIdx.x * 256 + threadIdx.x;
    f4 v = ((const f4*)x)[i];
    h4 hh;
    #pragma unroll
    for (int k = 0; k < 4; ++k) hh[k] = (_Float16)v[k];
    ((h4*)o)[i] = hh;
}

// W [512,512] fp32 -> Wt [512,512] f16 transposed (Wt[n][k] = W[k][n]).
__global__ __launch_bounds__(256) void wconv(const float* s0, const float* s1, const float* s2,
                                             _Float16* d0, _Float16* d1, _Float16* d2)
{
    const float* Sm = blockIdx.z == 0 ? s0 : blockIdx.z == 1 ? s1 : s2;
    _Float16* D = blockIdx.z == 0 ? d0 : blockIdx.z == 1 ? d1 : d2;
    __shared__ float t[32][33];
    const int x = threadIdx.x & 31, y = threadIdx.x >> 5;
    const int gx = blockIdx.x * 32, gy = blockIdx.y * 32;
    #pragma unroll
    for (int yy = y; yy < 32; yy += 8)
        t[yy][x] = Sm[(size_t)(gy + yy) * 512 + gx + x];
    __syncthreads();
    #pragma unroll
    for (int yy = y; yy < 32; yy += 8)
        D[(size_t)(gx + yy) * 512 + gy + x] = (_Float16)t[x][yy];
}

// ---------------------------------------------------------------------------
// ws layout (same as R6, 142.6 MiB < 160 MiB proven):
//   e    [0x0000000, 0x4000000)  8x2048x2048 f16 e[n][m]
//   mlq  [0x4000000, 0x4400000)  (m_t,l_t) float2 per (row, m-tile)
//   alpha[0x4400000, 0x4600000)  fp32
//   dec_h[0x4600000, 0x5600000)  f16 [bn][c]
//   Wvt/W1t/W2t [0x5600000, +3*512KB)
//   vT   [0x5800000, 0x6800000)  f16 [b][c][m]
//   g    [0x6800000, 0x7800000)  f16 [bn][c]
//   h    [0x7800000, 0x8800000)  f16 [bn][c2]
//   enc_h in d_out (dead before fc2 writes).
// ---------------------------------------------------------------------------
extern "C" void kernel_launch(void* const* d_in, const int* in_sizes, int n_in,
                              void* d_out, int out_size, void* d_ws, size_t ws_size,
                              hipStream_t stream)
{
    const float* dec   = (const float*)d_in[0];
    const float* enc   = (const float*)d_in[1];
    const float* trans = (const float*)d_in[2];
    const float* Wv = (const float*)d_in[3];
    const float* bv = (const float*)d_in[4];
    const float* W1 = (const float*)d_in[5];
    const float* b1 = (const float*)d_in[6];
    const float* W2 = (const float*)d_in[7];
    const float* b2 = (const float*)d_in[8];

    char* ws = (char*)d_ws;
    _Float16* e     = (_Float16*)ws;
    float*    mlq   = (float*)(ws + 0x4000000);
    float*    alpha = (float*)(ws + 0x4400000);
    _Float16* dec_h = (_Float16*)(ws + 0x4600000);
    _Float16* Wvt   = (_Float16*)(ws + 0x5600000);
    _Float16* W1t   = Wvt + 262144;
    _Float16* W2t   = Wvt + 524288;
    _Float16* vT    = (_Float16*)(ws + 0x5800000);
    _Float16* g     = (_Float16*)(ws + 0x6800000);
    _Float16* h     = (_Float16*)(ws + 0x7800000);
    _Float16* enc_h = (_Float16*)d_out;

    sconv<<<dim3(8192), 256, 0, stream>>>(dec, dec_h);
    sconv<<<dim3(8192), 256, 0, stream>>>(enc, enc_h);
    wconv<<<dim3(16, 16, 3), 256, 0, stream>>>(Wv, W1, W2, Wvt, W1t, W2t);

    // e[n][m] = exp(mask*scores - m_t):  A=enc (rows=m), B=dec (cols=n)
    gemm_mfma<0, 128, 1><<<dim3(2048), 256, 0, stream>>>(
        enc_h, (long)Mm * Cc, 512,
        dec_h, (long)Nn * Cc, 512,
        trans, (long)Nn * Mm, 2048, nullptr, mlq,
        e, (long)Nn * Mm, 2048, 512, 16);

    // per-row combine -> alpha
    combine_kernel<<<dim3(256), 64, 0, stream>>>(mlq, alpha);

    // v^T = (enc @ Wv + bv)^T  [b][c][m]   [SWZ2, GX=8]
    gemm_mfma<1, 64, 2><<<dim3(1024), 256, 0, stream>>>(
        enc_h, 0, 512, Wvt, 0, 512, bv, 0, 0, nullptr, nullptr,
        vT, 0, 0, 512, 8);

    // g[n][c] = dec_h*(1+tanh((alpha.e) @ v)):  A=vT (rows=c), B=e (cols=n)
    gemm_mfma<2, 128, 1><<<dim3(512), 256, 0, stream>>>(
        vT, (long)Cc * Mm, 2048,
        e, (long)Nn * Mm, 2048,
        nullptr, 0, 512, dec_h, alpha,
        g, (long)Nn * Cc, 512, 2048, 16);

    // h[n][c2] = relu(g @ W1 + b1):  A=W1^T (rows=c2), B=g (cols=n)
    gemm_mfma<3, 64, 0><<<dim3(256, 4), 256, 0, stream>>>(
        W1t, 0, 512, g, 0, 512, b1, 0, 0, nullptr, nullptr,
        h, 0, 512, 512, 0);

    // out[n][c3] = h @ W2 + b2:  A=W2^T (rows=c3), B=h (cols=n), fp32
    gemm_mfma<4, 64, 0><<<dim3(256, 4), 256, 0, stream>>>(
        W2t, 0, 512, h, 0, 512, b2, 0, 0, nullptr, nullptr,
        d_out, 0, 512, 512, 0);
}